// Round 1
// baseline (68203.912 us; speedup 1.0000x reference)
//
#include <hip/hip_runtime.h>
#include <math.h>

// Problem constants (fixed by setup_inputs): N=64, S=512, D=512, C=1024
#define Dd 512
#define Ss 512
#define Nb 64
#define Cc 1024
#define LN_EPS 1e-5f

__device__ __forceinline__ float gelu_f(float x) {
  // jax.nn.gelu default (approximate=True, tanh form)
  float x3 = x * x * x;
  return 0.5f * x * (1.0f + tanhf(0.7978845608028654f * (x + 0.044715f * x3)));
}

__device__ __forceinline__ float sigmoid_f(float x) {
  return 1.0f / (1.0f + expf(-x));
}

// block-wide (256 threads) reduction of two values
__device__ __forceinline__ void block_reduce_2(float& s, float& ss) {
#pragma unroll
  for (int off = 32; off > 0; off >>= 1) {
    s += __shfl_down(s, off, 64);
    ss += __shfl_down(ss, off, 64);
  }
  __shared__ float red[8];
  int lane = threadIdx.x & 63, wv = threadIdx.x >> 6;
  if (lane == 0) { red[wv] = s; red[4 + wv] = ss; }
  __syncthreads();
  s = red[0] + red[1] + red[2] + red[3];
  ss = red[4] + red[5] + red[6] + red[7];
}

// ht[n,d] = gs[n,d] = START[d]
__global__ void k_init(const float* __restrict__ start, float* __restrict__ ht,
                       float* __restrict__ gs) {
  int i = blockIdx.x * 256 + threadIdx.x;  // < 64*512
  float v = start[i & (Dd - 1)];
  ht[i] = v;
  gs[i] = v;
}

// out[r,c] = sum_k (A[r,k]*mask[r]) * W[k,c] + bias[c]
// M=32768, N=512, K=512. BM=BN=64, BK=16, 256 thr, 4x4 micro-tile.
__global__ __launch_bounds__(256) void k_gemm_init(
    const float* __restrict__ A, const float* __restrict__ mask,
    const float* __restrict__ W, const float* __restrict__ bias,
    float* __restrict__ out) {
  __shared__ float As[16][65];
  __shared__ float Bs[16][65];
  const int tid = threadIdx.x;
  const int bm = blockIdx.y * 64;
  const int bn = blockIdx.x * 64;
  const int tx = tid & 15;
  const int ty = tid >> 4;
  const int idx = tid * 4;
  const int am = idx >> 4;   // 0..63
  const int ak = idx & 15;   // 0,4,8,12
  const int bk = idx >> 6;   // 0..15
  const int bn2 = idx & 63;  // 0..60 step 4
  const float mrow = mask[bm + am];
  float acc[4][4] = {};
  for (int k0 = 0; k0 < Dd; k0 += 16) {
    float4 av = *(const float4*)(A + (size_t)(bm + am) * Dd + k0 + ak);
    As[ak + 0][am] = av.x * mrow;
    As[ak + 1][am] = av.y * mrow;
    As[ak + 2][am] = av.z * mrow;
    As[ak + 3][am] = av.w * mrow;
    float4 bv = *(const float4*)(W + (size_t)(k0 + bk) * Dd + bn + bn2);
    Bs[bk][bn2 + 0] = bv.x;
    Bs[bk][bn2 + 1] = bv.y;
    Bs[bk][bn2 + 2] = bv.z;
    Bs[bk][bn2 + 3] = bv.w;
    __syncthreads();
#pragma unroll
    for (int kk = 0; kk < 16; ++kk) {
      float a0 = As[kk][ty * 4 + 0], a1 = As[kk][ty * 4 + 1];
      float a2 = As[kk][ty * 4 + 2], a3 = As[kk][ty * 4 + 3];
      float b0 = Bs[kk][tx * 4 + 0], b1 = Bs[kk][tx * 4 + 1];
      float b2 = Bs[kk][tx * 4 + 2], b3 = Bs[kk][tx * 4 + 3];
      acc[0][0] = fmaf(a0, b0, acc[0][0]);
      acc[0][1] = fmaf(a0, b1, acc[0][1]);
      acc[0][2] = fmaf(a0, b2, acc[0][2]);
      acc[0][3] = fmaf(a0, b3, acc[0][3]);
      acc[1][0] = fmaf(a1, b0, acc[1][0]);
      acc[1][1] = fmaf(a1, b1, acc[1][1]);
      acc[1][2] = fmaf(a1, b2, acc[1][2]);
      acc[1][3] = fmaf(a1, b3, acc[1][3]);
      acc[2][0] = fmaf(a2, b0, acc[2][0]);
      acc[2][1] = fmaf(a2, b1, acc[2][1]);
      acc[2][2] = fmaf(a2, b2, acc[2][2]);
      acc[2][3] = fmaf(a2, b3, acc[2][3]);
      acc[3][0] = fmaf(a3, b0, acc[3][0]);
      acc[3][1] = fmaf(a3, b1, acc[3][1]);
      acc[3][2] = fmaf(a3, b2, acc[3][2]);
      acc[3][3] = fmaf(a3, b3, acc[3][3]);
    }
    __syncthreads();
  }
#pragma unroll
  for (int i2 = 0; i2 < 4; ++i2) {
    int row = bm + ty * 4 + i2;
#pragma unroll
    for (int j = 0; j < 4; ++j) {
      int col = bn + tx * 4 + j;
      out[(size_t)row * Dd + col] = acc[i2][j] + bias[col];
    }
  }
}

// in-place per-row LayerNorm * mask (row length 512), one block per row
__global__ __launch_bounds__(256) void k_ln_rows(
    float* __restrict__ io, const float* __restrict__ mask,
    const float* __restrict__ g, const float* __restrict__ b) {
  const int r = blockIdx.x;
  float* row = io + (size_t)r * Dd;
  const int tid = threadIdx.x;
  float x0 = row[tid], x1 = row[tid + 256];
  float s = x0 + x1, ss = x0 * x0 + x1 * x1;
  block_reduce_2(s, ss);
  float mean = s * (1.0f / Dd);
  float var = ss * (1.0f / Dd) - mean * mean;
  float rs = rsqrtf(var + LN_EPS);
  float m = mask[r];
  row[tid] = ((x0 - mean) * rs * g[tid] + b[tid]) * m;
  row[tid + 256] = ((x1 - mean) * rs * g[tid + 256] + b[tid + 256]) * m;
}

// inter = gelu([ht | x_t] @ W1 + b1). M=64, K=1024, N=1024.
// grid 128 blocks x 8 cols; thread = (row, 2 cols). cat chunk staged in LDS.
__global__ __launch_bounds__(256) void k_step_gemm1(
    const float* __restrict__ ht, const float* __restrict__ seq2,
    const float* __restrict__ W1, const float* __restrict__ b1,
    float* __restrict__ inter, int t) {
  __shared__ float Asl[64][65];
  const int tid = threadIdx.x;
  const int r = tid & 63;
  const int cs = tid >> 6;
  const int c0 = blockIdx.x * 8 + cs * 2;
  float acc0 = 0.f, acc1 = 0.f;
  const float* xbase = seq2 + (size_t)t * Dd;  // + n*S*D per row
  for (int k0 = 0; k0 < 2 * Dd; k0 += 64) {
#pragma unroll
    for (int i = 0; i < 4; ++i) {
      int vecIdx = tid + i * 256;       // 0..1023
      int rr = vecIdx >> 4;             // 0..63
      int kk = (vecIdx & 15) * 4;       // 0..60
      float4 v;
      if (k0 < Dd) {
        v = *(const float4*)(ht + rr * Dd + k0 + kk);
      } else {
        v = *(const float4*)(xbase + (size_t)rr * Ss * Dd + (k0 + kk - Dd));
      }
      Asl[rr][kk + 0] = v.x;
      Asl[rr][kk + 1] = v.y;
      Asl[rr][kk + 2] = v.z;
      Asl[rr][kk + 3] = v.w;
    }
    __syncthreads();
    const float* wp = W1 + (size_t)k0 * Cc + c0;
#pragma unroll 16
    for (int kk = 0; kk < 64; ++kk) {
      float2 w = *(const float2*)(wp + (size_t)kk * Cc);
      float a = Asl[r][kk];
      acc0 = fmaf(a, w.x, acc0);
      acc1 = fmaf(a, w.y, acc1);
    }
    __syncthreads();
  }
  acc0 += b1[c0];
  acc1 += b1[c0 + 1];
  inter[r * Cc + c0] = gelu_f(acc0);
  inter[r * Cc + c0 + 1] = gelu_f(acc1);
}

// contents = inter @ W2 + b2. M=64, K=1024, N=2048. grid 256 blocks x 8 cols.
__global__ __launch_bounds__(256) void k_step_gemm2(
    const float* __restrict__ inter, const float* __restrict__ W2,
    const float* __restrict__ b2, float* __restrict__ contents) {
  __shared__ float Asl[64][65];
  const int tid = threadIdx.x;
  const int r = tid & 63;
  const int cs = tid >> 6;
  const int c0 = blockIdx.x * 8 + cs * 2;
  float acc0 = 0.f, acc1 = 0.f;
  for (int k0 = 0; k0 < Cc; k0 += 64) {
#pragma unroll
    for (int i = 0; i < 4; ++i) {
      int vecIdx = tid + i * 256;
      int rr = vecIdx >> 4;
      int kk = (vecIdx & 15) * 4;
      float4 v = *(const float4*)(inter + rr * Cc + k0 + kk);
      Asl[rr][kk + 0] = v.x;
      Asl[rr][kk + 1] = v.y;
      Asl[rr][kk + 2] = v.z;
      Asl[rr][kk + 3] = v.w;
    }
    __syncthreads();
    const float* wp = W2 + (size_t)k0 * 2048 + c0;
#pragma unroll 16
    for (int kk = 0; kk < 64; ++kk) {
      float2 w = *(const float2*)(wp + (size_t)kk * 2048);
      float a = Asl[r][kk];
      acc0 = fmaf(a, w.x, acc0);
      acc1 = fmaf(a, w.y, acc1);
    }
    __syncthreads();
  }
  contents[r * 2048 + c0] = acc0 + b2[c0];
  contents[r * 2048 + c0 + 1] = acc1 + b2[c0 + 1];
}

// gates + z + LN -> ht_new; writes ht (unmasked), out_seq (masked, in-place
// over the consumed x_t slot), gs (masked blend). One block per batch row.
__global__ __launch_bounds__(256) void k_step_ln(
    const float* __restrict__ contents, float* __restrict__ ht,
    float* __restrict__ outseq, float* __restrict__ gs,
    const float* __restrict__ mask, const float* __restrict__ g,
    const float* __restrict__ b, int t) {
  const int n = blockIdx.x;
  const int tid = threadIdx.x;
  const float* crow = contents + n * 2048;
  float* htrow = ht + n * Dd;
  float* orow = outseq + (size_t)n * Ss * Dd + (size_t)t * Dd;
  float* grow = gs + n * Dd;
  const float m = mask[n * Ss + t];
  float z[2];
#pragma unroll
  for (int j = 0; j < 2; ++j) {
    int d = tid + j * 256;
    float f1 = sigmoid_f(crow[d]);
    float f2 = sigmoid_f(crow[Dd + d]);
    float ii = sigmoid_f(crow[2 * Dd + d]);
    float pp = crow[3 * Dd + d];
    z[j] = f1 * htrow[d] + f2 * orow[d] + ii * pp;
  }
  float s = z[0] + z[1];
  float ss = z[0] * z[0] + z[1] * z[1];
  block_reduce_2(s, ss);
  float mean = s * (1.0f / Dd);
  float var = ss * (1.0f / Dd) - mean * mean;
  float rs = rsqrtf(var + LN_EPS);
#pragma unroll
  for (int j = 0; j < 2; ++j) {
    int d = tid + j * 256;
    float hn = (z[j] - mean) * rs * g[d] + b[d];
    htrow[d] = hn;            // carry (unmasked)
    orow[d] = hn * m;         // out_seq
    grow[d] = m * hn + (1.0f - m) * grow[d];  // global_state
  }
}

extern "C" void kernel_launch(void* const* d_in, const int* in_sizes, int n_in,
                              void* d_out, int out_size, void* d_ws,
                              size_t ws_size, hipStream_t stream) {
  const float* seq = (const float*)d_in[0];     // (64,512,512)
  const float* mask = (const float*)d_in[1];    // (64,512)
  const float* START = (const float*)d_in[2];   // (512)
  const float* W_init = (const float*)d_in[3];  // (512,512)
  const float* b_init = (const float*)d_in[4];  // (512)
  const float* W1 = (const float*)d_in[5];      // (1024,1024)
  const float* b1 = (const float*)d_in[6];      // (1024)
  const float* W2 = (const float*)d_in[7];      // (1024,2048)
  const float* b2 = (const float*)d_in[8];      // (2048)
  const float* ln_g = (const float*)d_in[9];    // (512)
  const float* ln_b = (const float*)d_in[10];   // (512)

  float* out = (float*)d_out;
  float* out_seq = out;                        // 64*512*512 (doubles as seq2)
  float* gs = out + (size_t)Nb * Ss * Dd;      // 64*512

  float* ht = (float*)d_ws;                    // 64*512
  float* inter = ht + Nb * Dd;                 // 64*1024
  float* contents = inter + Nb * Cc;           // 64*2048

  // init carries
  k_init<<<(Nb * Dd) / 256, 256, 0, stream>>>(START, ht, gs);

  // prologue: seq2 = LN((seq*mask)@W_init + b_init)*mask, stored in out_seq
  dim3 ga(Dd / 64, (Nb * Ss) / 64);
  k_gemm_init<<<ga, 256, 0, stream>>>(seq, mask, W_init, b_init, out_seq);
  k_ln_rows<<<Nb * Ss, 256, 0, stream>>>(out_seq, mask, ln_g, ln_b);

  // scan
  for (int t = 0; t < Ss; ++t) {
    k_step_gemm1<<<Cc / 8, 256, 0, stream>>>(ht, out_seq, W1, b1, inter, t);
    k_step_gemm2<<<2048 / 8, 256, 0, stream>>>(inter, W2, b2, contents);
    k_step_ln<<<Nb, 256, 0, stream>>>(contents, ht, out_seq, gs, mask, ln_g,
                                      ln_b, t);
  }
}

// Round 2
// 65750.177 us; speedup vs baseline: 1.0373x; 1.0373x over previous
//
#include <hip/hip_runtime.h>
#include <hip/hip_cooperative_groups.h>
#include <math.h>

namespace cg = cooperative_groups;

// Problem constants (fixed by setup_inputs): N=64, S=512, D=512, C=1024
#define DD 512
#define SS 512
#define NB 64
#define CC 1024
#define FF 2048  // 4*D
#define LN_EPS 1e-5f

__device__ __forceinline__ float sigf(float x) {
  return 1.0f / (1.0f + __expf(-x));
}

// ---------------- prologue kernels (unchanged from round 0) ----------------

__global__ __launch_bounds__(256) void k_gemm_init(
    const float* __restrict__ A, const float* __restrict__ mask,
    const float* __restrict__ W, const float* __restrict__ bias,
    float* __restrict__ out) {
  __shared__ float As[16][65];
  __shared__ float Bs[16][65];
  const int tid = threadIdx.x;
  const int bm = blockIdx.y * 64;
  const int bn = blockIdx.x * 64;
  const int tx = tid & 15;
  const int ty = tid >> 4;
  const int idx = tid * 4;
  const int am = idx >> 4;
  const int ak = idx & 15;
  const int bk = idx >> 6;
  const int bn2 = idx & 63;
  const float mrow = mask[bm + am];
  float acc[4][4] = {};
  for (int k0 = 0; k0 < DD; k0 += 16) {
    float4 av = *(const float4*)(A + (size_t)(bm + am) * DD + k0 + ak);
    As[ak + 0][am] = av.x * mrow;
    As[ak + 1][am] = av.y * mrow;
    As[ak + 2][am] = av.z * mrow;
    As[ak + 3][am] = av.w * mrow;
    float4 bv = *(const float4*)(W + (size_t)(k0 + bk) * DD + bn + bn2);
    Bs[bk][bn2 + 0] = bv.x;
    Bs[bk][bn2 + 1] = bv.y;
    Bs[bk][bn2 + 2] = bv.z;
    Bs[bk][bn2 + 3] = bv.w;
    __syncthreads();
#pragma unroll
    for (int kk = 0; kk < 16; ++kk) {
      float a0 = As[kk][ty * 4 + 0], a1 = As[kk][ty * 4 + 1];
      float a2 = As[kk][ty * 4 + 2], a3 = As[kk][ty * 4 + 3];
      float b0 = Bs[kk][tx * 4 + 0], b1 = Bs[kk][tx * 4 + 1];
      float b2 = Bs[kk][tx * 4 + 2], b3 = Bs[kk][tx * 4 + 3];
      acc[0][0] = fmaf(a0, b0, acc[0][0]);
      acc[0][1] = fmaf(a0, b1, acc[0][1]);
      acc[0][2] = fmaf(a0, b2, acc[0][2]);
      acc[0][3] = fmaf(a0, b3, acc[0][3]);
      acc[1][0] = fmaf(a1, b0, acc[1][0]);
      acc[1][1] = fmaf(a1, b1, acc[1][1]);
      acc[1][2] = fmaf(a1, b2, acc[1][2]);
      acc[1][3] = fmaf(a1, b3, acc[1][3]);
      acc[2][0] = fmaf(a2, b0, acc[2][0]);
      acc[2][1] = fmaf(a2, b1, acc[2][1]);
      acc[2][2] = fmaf(a2, b2, acc[2][2]);
      acc[2][3] = fmaf(a2, b3, acc[2][3]);
      acc[3][0] = fmaf(a3, b0, acc[3][0]);
      acc[3][1] = fmaf(a3, b1, acc[3][1]);
      acc[3][2] = fmaf(a3, b2, acc[3][2]);
      acc[3][3] = fmaf(a3, b3, acc[3][3]);
    }
    __syncthreads();
  }
#pragma unroll
  for (int i2 = 0; i2 < 4; ++i2) {
    int row = bm + ty * 4 + i2;
#pragma unroll
    for (int j = 0; j < 4; ++j) {
      int col = bn + tx * 4 + j;
      out[(size_t)row * DD + col] = acc[i2][j] + bias[col];
    }
  }
}

__global__ __launch_bounds__(256) void k_ln_rows(
    float* __restrict__ io, const float* __restrict__ mask,
    const float* __restrict__ g, const float* __restrict__ b) {
  const int r = blockIdx.x;
  float* row = io + (size_t)r * DD;
  const int tid = threadIdx.x;
  float x0 = row[tid], x1 = row[tid + 256];
  float s = x0 + x1, ss = x0 * x0 + x1 * x1;
#pragma unroll
  for (int off = 32; off > 0; off >>= 1) {
    s += __shfl_down(s, off, 64);
    ss += __shfl_down(ss, off, 64);
  }
  __shared__ float red[8];
  int lane = tid & 63, wv = tid >> 6;
  if (lane == 0) { red[wv] = s; red[4 + wv] = ss; }
  __syncthreads();
  s = red[0] + red[1] + red[2] + red[3];
  ss = red[4] + red[5] + red[6] + red[7];
  float mean = s * (1.0f / DD);
  float var = ss * (1.0f / DD) - mean * mean;
  float rs = rsqrtf(var + LN_EPS);
  float m = mask[r];
  row[tid] = ((x0 - mean) * rs * g[tid] + b[tid]) * m;
  row[tid + 256] = ((x1 - mean) * rs * g[tid + 256] + b[tid + 256]) * m;
}

// ---------------- persistent scan kernel ----------------
// Grid: 256 blocks x 512 threads, cooperative. Block b owns:
//   - gemm1 output cols [4b, 4b+4)        (inter, C=1024)
//   - hidden dims d in {2b, 2b+1}         (z, ht, gs, out_seq, and the
//     4 gate columns {q*512+2b, q*512+2b+1} of gemm2)
// Per step: phaseA = [normalize prev z -> outputs] + gemm1 -> inter;
//           barrier; phaseB = gemm2 -> gates -> z + stat atomics; barrier.
// LayerNorm of ht is applied INLINE while staging cat (ht never stored).

__global__ __launch_bounds__(512, 1) void scan_kernel(
    float* __restrict__ outseq,          // d_out: (64,512,512), holds seq2
    float* __restrict__ gsout,           // d_out + N*S*D: (64,512)
    const float* __restrict__ mask,      // (64,512)
    const float* __restrict__ START,     // (512)
    const float* __restrict__ W1, const float* __restrict__ b1,
    const float* __restrict__ W2, const float* __restrict__ b2,
    const float* __restrict__ ln_g, const float* __restrict__ ln_b,
    float* __restrict__ zg,              // ws: (64,512)
    float* __restrict__ inter,           // ws: (64,1024)
    float* __restrict__ st_sum,          // ws: [2][64][32]
    float* __restrict__ st_ss) {         // ws: [2][64][32]
  cg::grid_group grid = cg::this_grid();
  const int b = blockIdx.x;     // 0..255
  const int tid = threadIdx.x;  // 0..511
  const int r = tid & 63;
  const int cs = (tid >> 6) & 3;  // col-group (phase A) / gate chunk q (phase B)
  const int kh = tid >> 8;        // K-half
  const int rr_a = tid >> 4;      // staging row (0..31)
  const int rr_b = rr_a + 32;
  const int kkst = (tid & 15) * 4;  // staging col
  const int cA = __builtin_amdgcn_readfirstlane(4 * b + cs);
  const int cB = __builtin_amdgcn_readfirstlane(cs * 512 + 2 * b);
  const int d0 = 2 * b;

  __shared__ float Asl[2][64][68];
  __shared__ float2 cbuf[4][64];
  __shared__ float smean[64];
  __shared__ float srs[64];
  __shared__ float pA[256];
  __shared__ float2 pB[256];

  float ht0 = 0.f, ht1 = 0.f, gs0 = 0.f, gs1 = 0.f, z0 = 0.f, z1 = 0.f;
  float gg0 = 0.f, gg1 = 0.f, bb0 = 0.f, bb1 = 0.f;
  if (tid < 64) {
    ht0 = START[d0];
    ht1 = START[d0 + 1];
    gs0 = ht0;
    gs1 = ht1;
    gg0 = ln_g[d0];
    gg1 = ln_g[d0 + 1];
    bb0 = ln_b[d0];
    bb1 = ln_b[d0 + 1];
  }

  for (int t = 0; t < SS; ++t) {
    // ---------------- phase A ----------------
    if (t == 0) {
      if (b == 0) {  // zero stats parity 0 before phase B(0) atomics
        for (int i = tid; i < 2048; i += 512) {
          st_sum[i] = 0.f;
          st_ss[i] = 0.f;
        }
      }
    } else {
      if (tid < 64) {
        const int par = ((t - 1) & 1) * 2048;
        const float* sp = st_sum + par + r * 32;
        const float* qp = st_ss + par + r * 32;
        float s = 0.f, ss = 0.f;
#pragma unroll
        for (int i2 = 0; i2 < 32; i2 += 4) {
          float4 a4 = *(const float4*)(sp + i2);
          float4 c4 = *(const float4*)(qp + i2);
          s += a4.x + a4.y + a4.z + a4.w;
          ss += c4.x + c4.y + c4.z + c4.w;
        }
        float mean = s * (1.0f / DD);
        float var = ss * (1.0f / DD) - mean * mean;
        float rsv = rsqrtf(var + LN_EPS);
        smean[r] = mean;
        srs[r] = rsv;
        float hn0 = (z0 - mean) * rsv * gg0 + bb0;
        float hn1 = (z1 - mean) * rsv * gg1 + bb1;
        float m = mask[r * SS + (t - 1)];
        float2 o2;
        o2.x = hn0 * m;
        o2.y = hn1 * m;
        *(float2*)(outseq + (size_t)r * SS * DD + (size_t)(t - 1) * DD + d0) = o2;
        gs0 = m * hn0 + (1.f - m) * gs0;
        gs1 = m * hn1 + (1.f - m) * gs1;
        ht0 = hn0;
        ht1 = hn1;
      }
      __syncthreads();
    }
    // ---- gemm1: inter = gelu(cat @ W1 + b1), cat staged w/ inline LN ----
    float acc = 0.f;
    for (int it = 0; it < 8; ++it) {
      const int k = it * 64 + kkst;
      if (t == 0) {
        float4 v = *(const float4*)(START + k);
        *(float4*)&Asl[0][rr_a][kkst] = v;
        *(float4*)&Asl[0][rr_b][kkst] = v;
      } else {
        float4 g4 = *(const float4*)(ln_g + k);
        float4 b4 = *(const float4*)(ln_b + k);
        {
          float4 z4 = *(const float4*)(zg + rr_a * DD + k);
          float mn = smean[rr_a], rv = srs[rr_a];
          float4 v;
          v.x = (z4.x - mn) * rv * g4.x + b4.x;
          v.y = (z4.y - mn) * rv * g4.y + b4.y;
          v.z = (z4.z - mn) * rv * g4.z + b4.z;
          v.w = (z4.w - mn) * rv * g4.w + b4.w;
          *(float4*)&Asl[0][rr_a][kkst] = v;
        }
        {
          float4 z4 = *(const float4*)(zg + rr_b * DD + k);
          float mn = smean[rr_b], rv = srs[rr_b];
          float4 v;
          v.x = (z4.x - mn) * rv * g4.x + b4.x;
          v.y = (z4.y - mn) * rv * g4.y + b4.y;
          v.z = (z4.z - mn) * rv * g4.z + b4.z;
          v.w = (z4.w - mn) * rv * g4.w + b4.w;
          *(float4*)&Asl[0][rr_b][kkst] = v;
        }
      }
      *(float4*)&Asl[1][rr_a][kkst] =
          *(const float4*)(outseq + (size_t)rr_a * SS * DD + (size_t)t * DD + k);
      *(float4*)&Asl[1][rr_b][kkst] =
          *(const float4*)(outseq + (size_t)rr_b * SS * DD + (size_t)t * DD + k);
      __syncthreads();
      const int kb = __builtin_amdgcn_readfirstlane(kh * 512 + it * 64);
      const float* wp = W1 + (size_t)kb * CC + cA;
#pragma unroll
      for (int kk = 0; kk < 64; kk += 4) {
        float4 a4 = *(const float4*)&Asl[kh][r][kk];
        acc = fmaf(a4.x, wp[(size_t)(kk + 0) * CC], acc);
        acc = fmaf(a4.y, wp[(size_t)(kk + 1) * CC], acc);
        acc = fmaf(a4.z, wp[(size_t)(kk + 2) * CC], acc);
        acc = fmaf(a4.w, wp[(size_t)(kk + 3) * CC], acc);
      }
      __syncthreads();
    }
    if (kh) pA[tid & 255] = acc;
    __syncthreads();
    if (!kh) {
      acc += pA[tid];
      acc += b1[cA];
      float u = 1.5957691216057308f * (acc + 0.044715f * acc * acc * acc);
      inter[r * CC + cA] = acc / (1.0f + __expf(-u));  // x*sigmoid(2u)=gelu
    }
    grid.sync();  // barrier 1: inter visible

    // ---------------- phase B ----------------
    if (b == 0) {  // zero next-parity stats (read-phase for it finished pre-barrier1)
      const int p2 = ((t + 1) & 1) * 2048;
      for (int i = tid; i < 2048; i += 512) {
        st_sum[p2 + i] = 0.f;
        st_ss[p2 + i] = 0.f;
      }
    }
    float a0 = 0.f, a1 = 0.f;
    for (int it = 0; it < 8; ++it) {
      const int k = it * 64 + kkst;
      *(float4*)&Asl[0][rr_a][kkst] = *(const float4*)(inter + rr_a * CC + k);
      *(float4*)&Asl[0][rr_b][kkst] = *(const float4*)(inter + rr_b * CC + k);
      *(float4*)&Asl[1][rr_a][kkst] = *(const float4*)(inter + rr_a * CC + 512 + k);
      *(float4*)&Asl[1][rr_b][kkst] = *(const float4*)(inter + rr_b * CC + 512 + k);
      __syncthreads();
      const int kb = __builtin_amdgcn_readfirstlane(kh * 512 + it * 64);
      const float* wp = W2 + (size_t)kb * FF + cB;
#pragma unroll
      for (int kk = 0; kk < 64; kk += 4) {
        float4 a4 = *(const float4*)&Asl[kh][r][kk];
        float2 w0 = *(const float2*)(wp + (size_t)(kk + 0) * FF);
        float2 w1 = *(const float2*)(wp + (size_t)(kk + 1) * FF);
        float2 w2 = *(const float2*)(wp + (size_t)(kk + 2) * FF);
        float2 w3 = *(const float2*)(wp + (size_t)(kk + 3) * FF);
        a0 = fmaf(a4.x, w0.x, a0);
        a1 = fmaf(a4.x, w0.y, a1);
        a0 = fmaf(a4.y, w1.x, a0);
        a1 = fmaf(a4.y, w1.y, a1);
        a0 = fmaf(a4.z, w2.x, a0);
        a1 = fmaf(a4.z, w2.y, a1);
        a0 = fmaf(a4.w, w3.x, a0);
        a1 = fmaf(a4.w, w3.y, a1);
      }
      __syncthreads();
    }
    if (kh) pB[tid & 255] = make_float2(a0, a1);
    __syncthreads();
    if (!kh) {
      float2 p = pB[tid];
      a0 += p.x + b2[cB];
      a1 += p.y + b2[cB + 1];
      cbuf[cs][r] = make_float2(a0, a1);
    }
    __syncthreads();
    if (tid < 64) {
      float2 c0 = cbuf[0][r], c1 = cbuf[1][r], c2 = cbuf[2][r], c3 = cbuf[3][r];
      float2 x2 =
          *(const float2*)(outseq + (size_t)r * SS * DD + (size_t)t * DD + d0);
      z0 = sigf(c0.x) * ht0 + sigf(c1.x) * x2.x + sigf(c2.x) * c3.x;
      z1 = sigf(c0.y) * ht1 + sigf(c1.y) * x2.y + sigf(c2.y) * c3.y;
      *(float2*)(zg + r * DD + d0) = make_float2(z0, z1);
      const int par = (t & 1) * 2048;
      const int slot = b & 31;
      atomicAdd(st_sum + par + r * 32 + slot, z0 + z1);
      atomicAdd(st_ss + par + r * 32 + slot, z0 * z0 + z1 * z1);
    }
    grid.sync();  // barrier 2: z + stats visible
  }

  // ---------------- final flush (outputs of step 511) ----------------
  if (tid < 64) {
    const int par = ((SS - 1) & 1) * 2048;
    const float* sp = st_sum + par + r * 32;
    const float* qp = st_ss + par + r * 32;
    float s = 0.f, ss = 0.f;
#pragma unroll
    for (int i2 = 0; i2 < 32; i2 += 4) {
      float4 a4 = *(const float4*)(sp + i2);
      float4 c4 = *(const float4*)(qp + i2);
      s += a4.x + a4.y + a4.z + a4.w;
      ss += c4.x + c4.y + c4.z + c4.w;
    }
    float mean = s * (1.0f / DD);
    float var = ss * (1.0f / DD) - mean * mean;
    float rsv = rsqrtf(var + LN_EPS);
    float hn0 = (z0 - mean) * rsv * gg0 + bb0;
    float hn1 = (z1 - mean) * rsv * gg1 + bb1;
    float m = mask[r * SS + (SS - 1)];
    float2 o2;
    o2.x = hn0 * m;
    o2.y = hn1 * m;
    *(float2*)(outseq + (size_t)r * SS * DD + (size_t)(SS - 1) * DD + d0) = o2;
    gs0 = m * hn0 + (1.f - m) * gs0;
    gs1 = m * hn1 + (1.f - m) * gs1;
    *(float2*)(gsout + r * DD + d0) = make_float2(gs0, gs1);
  }
}

// ---------------- host ----------------

extern "C" void kernel_launch(void* const* d_in, const int* in_sizes, int n_in,
                              void* d_out, int out_size, void* d_ws,
                              size_t ws_size, hipStream_t stream) {
  const float* seq = (const float*)d_in[0];     // (64,512,512)
  const float* mask = (const float*)d_in[1];    // (64,512)
  const float* START = (const float*)d_in[2];   // (512)
  const float* W_init = (const float*)d_in[3];  // (512,512)
  const float* b_init = (const float*)d_in[4];  // (512)
  const float* W1 = (const float*)d_in[5];      // (1024,1024)
  const float* b1 = (const float*)d_in[6];      // (1024)
  const float* W2 = (const float*)d_in[7];      // (1024,2048)
  const float* b2 = (const float*)d_in[8];      // (2048)
  const float* ln_g = (const float*)d_in[9];    // (512)
  const float* ln_b = (const float*)d_in[10];   // (512)

  float* out = (float*)d_out;
  float* outseq = out;                          // (64,512,512); holds seq2
  float* gsout = out + (size_t)NB * SS * DD;    // (64,512)

  float* zg = (float*)d_ws;                     // 64*512
  float* inter = zg + NB * DD;                  // 64*1024
  float* st_sum = inter + NB * CC;              // 2*64*32
  float* st_ss = st_sum + 2 * 64 * 32;          // 2*64*32

  // prologue: seq2 = LN((seq*mask)@W_init + b_init)*mask  -> outseq
  dim3 ga(DD / 64, (NB * SS) / 64);
  k_gemm_init<<<ga, 256, 0, stream>>>(seq, mask, W_init, b_init, outseq);
  k_ln_rows<<<NB * SS, 256, 0, stream>>>(outseq, mask, ln_g, ln_b);

  // persistent cooperative scan
  void* args[] = {&outseq, &gsout, &mask, &START, &W1, &b1, &W2,
                  &b2,     &ln_g,  &ln_b, &zg,    &inter, &st_sum, &st_ss};
  hipLaunchCooperativeKernel((void*)scan_kernel, dim3(256), dim3(512), args, 0,
                             stream);
}

// Round 3
// 42274.561 us; speedup vs baseline: 1.6134x; 1.5553x over previous
//
#include <hip/hip_runtime.h>
#include <hip/hip_cooperative_groups.h>
#include <math.h>

namespace cg = cooperative_groups;

// Problem constants: N=64, S=512, D=512, C=1024
#define DD 512
#define SS 512
#define NB 64
#define CC 1024
#define FF 2048
#define LN_EPS 1e-5f

__device__ __forceinline__ float sigf(float x) {
  return 1.0f / (1.0f + __expf(-x));
}
__device__ __forceinline__ float geluf(float x) {
  // x * sigmoid(2*0.7978845608*(x+0.044715 x^3)) == jax tanh-gelu
  float u = 1.5957691216057308f * (x + 0.044715f * x * x * x);
  return x / (1.0f + __expf(-u));
}

// ---------------- prologue: seq2 = LN((seq*mask)@W_init+b_init)*mask ------
__global__ __launch_bounds__(256) void k_gemm_init(
    const float* __restrict__ A, const float* __restrict__ mask,
    const float* __restrict__ W, const float* __restrict__ bias,
    float* __restrict__ out) {
  __shared__ float As[16][65];
  __shared__ float Bs[16][65];
  const int tid = threadIdx.x;
  const int bm = blockIdx.y * 64;
  const int bn = blockIdx.x * 64;
  const int tx = tid & 15;
  const int ty = tid >> 4;
  const int idx = tid * 4;
  const int am = idx >> 4;
  const int ak = idx & 15;
  const int bk = idx >> 6;
  const int bn2 = idx & 63;
  const float mrow = mask[bm + am];
  float acc[4][4] = {};
  for (int k0 = 0; k0 < DD; k0 += 16) {
    float4 av = *(const float4*)(A + (size_t)(bm + am) * DD + k0 + ak);
    As[ak + 0][am] = av.x * mrow;
    As[ak + 1][am] = av.y * mrow;
    As[ak + 2][am] = av.z * mrow;
    As[ak + 3][am] = av.w * mrow;
    float4 bv = *(const float4*)(W + (size_t)(k0 + bk) * DD + bn + bn2);
    Bs[bk][bn2 + 0] = bv.x;
    Bs[bk][bn2 + 1] = bv.y;
    Bs[bk][bn2 + 2] = bv.z;
    Bs[bk][bn2 + 3] = bv.w;
    __syncthreads();
#pragma unroll
    for (int kk = 0; kk < 16; ++kk) {
      float a0 = As[kk][ty * 4 + 0], a1 = As[kk][ty * 4 + 1];
      float a2 = As[kk][ty * 4 + 2], a3 = As[kk][ty * 4 + 3];
      float b0 = Bs[kk][tx * 4 + 0], b1v = Bs[kk][tx * 4 + 1];
      float b2v = Bs[kk][tx * 4 + 2], b3 = Bs[kk][tx * 4 + 3];
      acc[0][0] = fmaf(a0, b0, acc[0][0]);
      acc[0][1] = fmaf(a0, b1v, acc[0][1]);
      acc[0][2] = fmaf(a0, b2v, acc[0][2]);
      acc[0][3] = fmaf(a0, b3, acc[0][3]);
      acc[1][0] = fmaf(a1, b0, acc[1][0]);
      acc[1][1] = fmaf(a1, b1v, acc[1][1]);
      acc[1][2] = fmaf(a1, b2v, acc[1][2]);
      acc[1][3] = fmaf(a1, b3, acc[1][3]);
      acc[2][0] = fmaf(a2, b0, acc[2][0]);
      acc[2][1] = fmaf(a2, b1v, acc[2][1]);
      acc[2][2] = fmaf(a2, b2v, acc[2][2]);
      acc[2][3] = fmaf(a2, b3, acc[2][3]);
      acc[3][0] = fmaf(a3, b0, acc[3][0]);
      acc[3][1] = fmaf(a3, b1v, acc[3][1]);
      acc[3][2] = fmaf(a3, b2v, acc[3][2]);
      acc[3][3] = fmaf(a3, b3, acc[3][3]);
    }
    __syncthreads();
  }
#pragma unroll
  for (int i2 = 0; i2 < 4; ++i2) {
    int row = bm + ty * 4 + i2;
#pragma unroll
    for (int j = 0; j < 4; ++j) {
      int col = bn + tx * 4 + j;
      out[(size_t)row * DD + col] = acc[i2][j] + bias[col];
    }
  }
}

__global__ __launch_bounds__(256) void k_ln_rows(
    float* __restrict__ io, const float* __restrict__ mask,
    const float* __restrict__ g, const float* __restrict__ b) {
  const int r = blockIdx.x;
  float* row = io + (size_t)r * DD;
  const int tid = threadIdx.x;
  float x0 = row[tid], x1 = row[tid + 256];
  float s = x0 + x1, ss = x0 * x0 + x1 * x1;
#pragma unroll
  for (int off = 32; off > 0; off >>= 1) {
    s += __shfl_down(s, off, 64);
    ss += __shfl_down(ss, off, 64);
  }
  __shared__ float red[8];
  int lane = tid & 63, wv = tid >> 6;
  if (lane == 0) { red[wv] = s; red[4 + wv] = ss; }
  __syncthreads();
  s = red[0] + red[1] + red[2] + red[3];
  ss = red[4] + red[5] + red[6] + red[7];
  float mean = s * (1.0f / DD);
  float var = ss * (1.0f / DD) - mean * mean;
  float rs = rsqrtf(var + LN_EPS);
  float m = mask[r];
  row[tid] = ((x0 - mean) * rs * g[tid] + b[tid]) * m;
  row[tid + 256] = ((x1 - mean) * rs * g[tid + 256] + b[tid + 256]) * m;
}

// ---- transpose seq2 (n,t,k) -> xT[t][k][n]  (coalesced both sides) ------
__global__ __launch_bounds__(256) void k_xt(const float* __restrict__ seq2,
                                            float* __restrict__ xT) {
  __shared__ float tl[64][65];
  const int t = blockIdx.x;
  const int kt = blockIdx.y * 64;
  const int n = threadIdx.x >> 2;
  const int f = threadIdx.x & 3;
#pragma unroll
  for (int u = 0; u < 4; ++u) {
    int k = f * 16 + u * 4;
    float4 v = *(const float4*)(seq2 + ((size_t)n * SS + t) * DD + kt + k);
    tl[k + 0][n] = v.x;
    tl[k + 1][n] = v.y;
    tl[k + 2][n] = v.z;
    tl[k + 3][n] = v.w;
  }
  __syncthreads();
  const int k2 = threadIdx.x >> 2;
#pragma unroll
  for (int u = 0; u < 4; ++u) {
    int nn = f * 16 + u * 4;
    float4 v = make_float4(tl[k2][nn], tl[k2][nn + 1], tl[k2][nn + 2],
                           tl[k2][nn + 3]);
    *(float4*)(xT + ((size_t)t * DD + kt + k2) * 64 + nn) = v;
  }
}

// ---- pack W1 per block: W1p[b][k][c] = (k<512? g[k]:1) * W1[k][4b+c] ----
__global__ __launch_bounds__(256) void k_pack1(const float* __restrict__ W1,
                                               const float* __restrict__ ln_g,
                                               float* __restrict__ W1p) {
  int i = blockIdx.x * 256 + threadIdx.x;  // < 1M
  int bb = i >> 12;
  int k = (i >> 2) & 1023;
  int c = i & 3;
  float v = W1[(size_t)k * CC + bb * 4 + c];
  if (k < 512) v *= ln_g[k];
  W1p[i] = v;
}

// ---- pack W2 per block: W2p[g][k][q*2+j] = W2[k][q*512+2g+j] -------------
__global__ __launch_bounds__(256) void k_pack2(const float* __restrict__ W2,
                                               float* __restrict__ W2p) {
  int i = blockIdx.x * 256 + threadIdx.x;  // < 2M
  int g = i >> 13;
  int k = (i >> 3) & 1023;
  int q = (i >> 1) & 3;
  int j = i & 1;
  W2p[i] = W2[(size_t)k * FF + q * 512 + 2 * g + j];
}

// ---- column sums: Q[c]=sum g_k W1[k,c]; Bln[c]=sum b_k W1[k,c]+b1[c];
//      H0[c]=sum START_k W1[k,c]+b1[c]   (k < 512) -------------------------
__global__ __launch_bounds__(128) void k_cols(
    const float* __restrict__ W1, const float* __restrict__ b1,
    const float* __restrict__ ln_g, const float* __restrict__ ln_b,
    const float* __restrict__ START, float* __restrict__ Qc,
    float* __restrict__ Blnc, float* __restrict__ H0c) {
  int c = blockIdx.x * 128 + threadIdx.x;  // grid 8*128 = 1024
  float q = 0.f, bl = 0.f, h = 0.f;
  for (int k = 0; k < 512; ++k) {
    float wv = W1[(size_t)k * CC + c];
    q = fmaf(ln_g[k], wv, q);
    bl = fmaf(ln_b[k], wv, bl);
    h = fmaf(START[k], wv, h);
  }
  float bias = b1[c];
  Qc[c] = q;
  Blnc[c] = bl + bias;
  H0c[c] = h + bias;
}

// ---------------- persistent scan ----------------------------------------
// 256 blocks x 512 thr. Block b owns gemm1 cols [4b,4b+4), gemm2 cols
// {q*512+2b, q*512+2b+1}, hidden dims {2b,2b+1}. Waves = 8-way K-split.
// Weights: private packed slices (s_load, L2-resident). Activations: all
// transposed ([k][row]) so per-lane loads are coalesced.
__global__ __launch_bounds__(512, 1) void scan_kernel(
    float* __restrict__ outseq, float* __restrict__ gsout,
    const float* __restrict__ mask, const float* __restrict__ START,
    const float* __restrict__ W1p, const float* __restrict__ W2p,
    const float* __restrict__ b2, const float* __restrict__ ln_g,
    const float* __restrict__ ln_b, const float* __restrict__ Qc,
    const float* __restrict__ Blnc, const float* __restrict__ H0c,
    float* __restrict__ interT, float* __restrict__ zT,
    float* __restrict__ st_sum, float* __restrict__ st_ss,
    const float* __restrict__ xT, const int use_xt) {
  cg::grid_group grid = cg::this_grid();
  const int b = blockIdx.x;
  const int tid = threadIdx.x;
  const int w = tid >> 6;
  const int lane = tid & 63;
  const int d0 = 2 * b;

  __shared__ float4 pA4[8][64];
  __shared__ float4 pB4[8][64][2];

  // owner state: thread tid<64 <-> row r=tid, dims {d0, d0+1}
  float ht0 = 0, ht1 = 0, gs0 = 0, gs1 = 0, z0 = 0, z1 = 0;
  float gg0 = 0, gg1 = 0, bb0 = 0, bb1 = 0, mn = 0, rv = 0;
  if (tid < 64) {
    ht0 = START[d0];
    ht1 = START[d0 + 1];
    gs0 = ht0;
    gs1 = ht1;
    gg0 = ln_g[d0];
    gg1 = ln_g[d0 + 1];
    bb0 = ln_b[d0];
    bb1 = ln_b[d0 + 1];
  }
  const float4 Q4 = *(const float4*)(Qc + 4 * b);
  const float4 Bl4 = *(const float4*)(Blnc + 4 * b);
  const float4 H04 = *(const float4*)(H0c + 4 * b);
  float bb2[8];
#pragma unroll
  for (int q = 0; q < 4; ++q) {
    bb2[2 * q] = b2[q * 512 + d0];
    bb2[2 * q + 1] = b2[q * 512 + d0 + 1];
  }

  for (int t = 0; t < SS; ++t) {
    // ---------- A-head: finalize step t-1 (owners) ----------
    if (t > 0 && tid < 64) {
      const int par = ((t - 1) & 1) << 11;
      const float* sp = st_sum + par + (tid << 5);
      const float* qp = st_ss + par + (tid << 5);
      float s = 0.f, ss = 0.f;
#pragma unroll
      for (int i = 0; i < 32; i += 4) {
        float4 a4 = *(const float4*)(sp + i);
        float4 c4 = *(const float4*)(qp + i);
        s += a4.x + a4.y + a4.z + a4.w;
        ss += c4.x + c4.y + c4.z + c4.w;
      }
      float mean = s * (1.0f / DD);
      float var = ss * (1.0f / DD) - mean * mean;
      float rsv = rsqrtf(var + LN_EPS);
      mn = mean;
      rv = rsv;
      float hn0 = (z0 - mean) * rsv * gg0 + bb0;
      float hn1 = (z1 - mean) * rsv * gg1 + bb1;
      float m = mask[tid * SS + (t - 1)];
      *(float2*)(outseq + (size_t)tid * SS * DD + (size_t)(t - 1) * DD + d0) =
          make_float2(hn0 * m, hn1 * m);
      gs0 = m * hn0 + (1.0f - m) * gs0;
      gs1 = m * hn1 + (1.0f - m) * gs1;
      ht0 = hn0;
      ht1 = hn1;
    }
    if (b == 0) {  // zero parity t&1 (used by B(t) atomics, after barrier 1)
      const int parz = (t & 1) << 11;
      for (int i = tid; i < 2048; i += 512) {
        st_sum[parz + i] = 0.f;
        st_ss[parz + i] = 0.f;
      }
    }
    // ---------- A waves: gemm1 partials ----------
    {
      const int k0 = w << 7;
      float4 acc = make_float4(0.f, 0.f, 0.f, 0.f);
      const float* wp = W1p + ((size_t)b << 12) + (k0 << 2);
      if (w < 4) {
        if (t > 0) {  // P-part over raw z (g folded into W1p)
          const float* zp = zT + k0 * 64 + lane;
#pragma unroll 2
          for (int i = 0; i < 128; i += 4) {
            const float* wr = wp + (i << 2);
#pragma unroll
            for (int j = 0; j < 4; ++j) {
              float zv = zp[(i + j) << 6];
              acc.x = fmaf(zv, wr[4 * j + 0], acc.x);
              acc.y = fmaf(zv, wr[4 * j + 1], acc.y);
              acc.z = fmaf(zv, wr[4 * j + 2], acc.z);
              acc.w = fmaf(zv, wr[4 * j + 3], acc.w);
            }
          }
        }
      } else {
        const int kx = k0 - 512;
        if (use_xt) {
          const float* xp = xT + ((size_t)t * DD + kx) * 64 + lane;
#pragma unroll 2
          for (int i = 0; i < 128; i += 4) {
            const float* wr = wp + (i << 2);
#pragma unroll
            for (int j = 0; j < 4; ++j) {
              float xv = xp[(i + j) << 6];
              acc.x = fmaf(xv, wr[4 * j + 0], acc.x);
              acc.y = fmaf(xv, wr[4 * j + 1], acc.y);
              acc.z = fmaf(xv, wr[4 * j + 2], acc.z);
              acc.w = fmaf(xv, wr[4 * j + 3], acc.w);
            }
          }
        } else {  // fallback: per-lane gather from seq2 layout
          const float* op = outseq + (size_t)lane * SS * DD + (size_t)t * DD + kx;
#pragma unroll 2
          for (int i = 0; i < 128; i += 4) {
            float4 xv = *(const float4*)(op + i);
            const float* wr = wp + (i << 2);
            acc.x = fmaf(xv.x, wr[0], acc.x);
            acc.y = fmaf(xv.x, wr[1], acc.y);
            acc.z = fmaf(xv.x, wr[2], acc.z);
            acc.w = fmaf(xv.x, wr[3], acc.w);
            acc.x = fmaf(xv.y, wr[4], acc.x);
            acc.y = fmaf(xv.y, wr[5], acc.y);
            acc.z = fmaf(xv.y, wr[6], acc.z);
            acc.w = fmaf(xv.y, wr[7], acc.w);
            acc.x = fmaf(xv.z, wr[8], acc.x);
            acc.y = fmaf(xv.z, wr[9], acc.y);
            acc.z = fmaf(xv.z, wr[10], acc.z);
            acc.w = fmaf(xv.z, wr[11], acc.w);
            acc.x = fmaf(xv.w, wr[12], acc.x);
            acc.y = fmaf(xv.w, wr[13], acc.y);
            acc.z = fmaf(xv.w, wr[14], acc.z);
            acc.w = fmaf(xv.w, wr[15], acc.w);
          }
        }
      }
      pA4[w][lane] = acc;
    }
    __syncthreads();
    // ---------- A-tail: epilogue (LN fold) + gelu -> interT ----------
    if (tid < 64) {
      float4 P = pA4[0][tid];
      float4 X = pA4[4][tid];
#pragma unroll
      for (int ww = 1; ww < 4; ++ww) {
        float4 p = pA4[ww][tid];
        P.x += p.x; P.y += p.y; P.z += p.z; P.w += p.w;
        float4 x4 = pA4[ww + 4][tid];
        X.x += x4.x; X.y += x4.y; X.z += x4.z; X.w += x4.w;
      }
      float4 o;
      if (t > 0) {
        float c1 = -rv * mn;
        o.x = fmaf(rv, P.x, fmaf(c1, Q4.x, Bl4.x)) + X.x;
        o.y = fmaf(rv, P.y, fmaf(c1, Q4.y, Bl4.y)) + X.y;
        o.z = fmaf(rv, P.z, fmaf(c1, Q4.z, Bl4.z)) + X.z;
        o.w = fmaf(rv, P.w, fmaf(c1, Q4.w, Bl4.w)) + X.w;
      } else {
        o.x = H04.x + X.x;
        o.y = H04.y + X.y;
        o.z = H04.z + X.z;
        o.w = H04.w + X.w;
      }
      interT[(4 * b + 0) * 64 + tid] = geluf(o.x);
      interT[(4 * b + 1) * 64 + tid] = geluf(o.y);
      interT[(4 * b + 2) * 64 + tid] = geluf(o.z);
      interT[(4 * b + 3) * 64 + tid] = geluf(o.w);
    }
    grid.sync();  // barrier 1: interT visible
    // ---------- B waves: gemm2 partials ----------
    {
      const int k0 = w << 7;
      float a0 = 0, a1 = 0, a2 = 0, a3 = 0, a4v = 0, a5 = 0, a6 = 0, a7 = 0;
      const float* w2 = W2p + ((size_t)b << 13) + (k0 << 3);
      const float* ip = interT + k0 * 64 + lane;
#pragma unroll 4
      for (int i = 0; i < 128; ++i) {
        float v = ip[i << 6];
        const float* wr = w2 + (i << 3);
        a0 = fmaf(v, wr[0], a0);
        a1 = fmaf(v, wr[1], a1);
        a2 = fmaf(v, wr[2], a2);
        a3 = fmaf(v, wr[3], a3);
        a4v = fmaf(v, wr[4], a4v);
        a5 = fmaf(v, wr[5], a5);
        a6 = fmaf(v, wr[6], a6);
        a7 = fmaf(v, wr[7], a7);
      }
      pB4[w][lane][0] = make_float4(a0, a1, a2, a3);
      pB4[w][lane][1] = make_float4(a4v, a5, a6, a7);
    }
    __syncthreads();
    // ---------- B-tail: gates -> z, stats atomics (owners) ----------
    if (tid < 64) {
      float4 lo = pB4[0][tid][0];
      float4 hi = pB4[0][tid][1];
#pragma unroll
      for (int ww = 1; ww < 8; ++ww) {
        float4 p = pB4[ww][tid][0];
        lo.x += p.x; lo.y += p.y; lo.z += p.z; lo.w += p.w;
        float4 q = pB4[ww][tid][1];
        hi.x += q.x; hi.y += q.y; hi.z += q.z; hi.w += q.w;
      }
      lo.x += bb2[0]; lo.y += bb2[1]; lo.z += bb2[2]; lo.w += bb2[3];
      hi.x += bb2[4]; hi.y += bb2[5]; hi.z += bb2[6]; hi.w += bb2[7];
      float x0, x1;
      if (use_xt) {
        x0 = xT[((size_t)t * DD + d0) * 64 + tid];
        x1 = xT[((size_t)t * DD + d0 + 1) * 64 + tid];
      } else {
        float2 x2 =
            *(const float2*)(outseq + (size_t)tid * SS * DD + (size_t)t * DD + d0);
        x0 = x2.x;
        x1 = x2.y;
      }
      // lo = (f1_d0, f1_d1, f2_d0, f2_d1); hi = (i_d0, i_d1, p_d0, p_d1)
      z0 = sigf(lo.x) * ht0 + sigf(lo.z) * x0 + sigf(hi.x) * hi.z;
      z1 = sigf(lo.y) * ht1 + sigf(lo.w) * x1 + sigf(hi.y) * hi.w;
      zT[d0 * 64 + tid] = z0;
      zT[(d0 + 1) * 64 + tid] = z1;
      const int par = (t & 1) << 11;
      const int slot = b & 31;
      atomicAdd(st_sum + par + (tid << 5) + slot, z0 + z1);
      atomicAdd(st_ss + par + (tid << 5) + slot, z0 * z0 + z1 * z1);
    }
    grid.sync();  // barrier 2: z + stats visible
  }
  // ---------- flush step 511 ----------
  if (tid < 64) {
    const int par = ((SS - 1) & 1) << 11;
    const float* sp = st_sum + par + (tid << 5);
    const float* qp = st_ss + par + (tid << 5);
    float s = 0.f, ss = 0.f;
#pragma unroll
    for (int i = 0; i < 32; i += 4) {
      float4 a4 = *(const float4*)(sp + i);
      float4 c4 = *(const float4*)(qp + i);
      s += a4.x + a4.y + a4.z + a4.w;
      ss += c4.x + c4.y + c4.z + c4.w;
    }
    float mean = s * (1.0f / DD);
    float var = ss * (1.0f / DD) - mean * mean;
    float rsv = rsqrtf(var + LN_EPS);
    float hn0 = (z0 - mean) * rsv * gg0 + bb0;
    float hn1 = (z1 - mean) * rsv * gg1 + bb1;
    float m = mask[tid * SS + (SS - 1)];
    *(float2*)(outseq + (size_t)tid * SS * DD + (size_t)(SS - 1) * DD + d0) =
        make_float2(hn0 * m, hn1 * m);
    gs0 = m * hn0 + (1.0f - m) * gs0;
    gs1 = m * hn1 + (1.0f - m) * gs1;
    *(float2*)(gsout + tid * DD + d0) = make_float2(gs0, gs1);
  }
}

// ---------------- host ----------------------------------------------------
extern "C" void kernel_launch(void* const* d_in, const int* in_sizes, int n_in,
                              void* d_out, int out_size, void* d_ws,
                              size_t ws_size, hipStream_t stream) {
  const float* seq = (const float*)d_in[0];
  const float* mask = (const float*)d_in[1];
  const float* START = (const float*)d_in[2];
  const float* W_init = (const float*)d_in[3];
  const float* b_init = (const float*)d_in[4];
  const float* W1 = (const float*)d_in[5];
  const float* b1 = (const float*)d_in[6];
  const float* W2 = (const float*)d_in[7];
  const float* b2 = (const float*)d_in[8];
  const float* ln_g = (const float*)d_in[9];
  const float* ln_b = (const float*)d_in[10];

  float* out = (float*)d_out;
  float* outseq = out;
  float* gsout = out + (size_t)NB * SS * DD;

  float* W1p = (float*)d_ws;              // 1,048,576
  float* W2p = W1p + 1048576;             // 2,097,152
  float* interT = W2p + 2097152;          // 65,536
  float* zT = interT + 65536;             // 32,768
  float* st_sum = zT + 32768;             // 4,096 (2 parities)
  float* st_ss = st_sum + 4096;           // 4,096
  float* Qc = st_ss + 4096;               // 1,024
  float* Blnc = Qc + 1024;                // 1,024
  float* H0c = Blnc + 1024;               // 1,024
  float* xT = H0c + 1024;                 // 16,777,216 (optional)
  const size_t base_bytes = (size_t)(3255296) * 4;
  const int use_xt = (ws_size >= base_bytes + (size_t)16777216 * 4) ? 1 : 0;

  // prologue: seq2 -> outseq (scan overwrites it slot-by-slot)
  dim3 ga(DD / 64, (NB * SS) / 64);
  k_gemm_init<<<ga, 256, 0, stream>>>(seq, mask, W_init, b_init, outseq);
  k_ln_rows<<<NB * SS, 256, 0, stream>>>(outseq, mask, ln_g, ln_b);
  if (use_xt) {
    k_xt<<<dim3(SS, 8), 256, 0, stream>>>(outseq, xT);
  }
  k_pack1<<<4096, 256, 0, stream>>>(W1, ln_g, W1p);
  k_pack2<<<8192, 256, 0, stream>>>(W2, W2p);
  k_cols<<<8, 128, 0, stream>>>(W1, b1, ln_g, ln_b, START, Qc, Blnc, H0c);

  void* args[] = {&outseq, &gsout, &mask, &START, &W1p, &W2p, &b2,
                  &ln_g,   &ln_b,  &Qc,   &Blnc,  &H0c, &interT, &zT,
                  &st_sum, &st_ss, &xT,   (void*)&use_xt};
  // note: args order must match kernel params exactly
  static int use_xt_copy;
  use_xt_copy = use_xt;
  void* args2[] = {&outseq, &gsout, &mask, &START, &W1p, &W2p, &b2,
                   &ln_g,   &ln_b,  &Qc,   &Blnc,  &H0c, &interT, &zT,
                   &st_sum, &st_ss, &xT,   &use_xt_copy};
  (void)args;
  hipLaunchCooperativeKernel((void*)scan_kernel, dim3(256), dim3(512), args2, 0,
                             stream);
}